// Round 4
// baseline (118.328 us; speedup 1.0000x reference)
//
#include <hip/hip_runtime.h>

#define NBATCH 4096
#define OUT2 (NBATCH * 64)

typedef _Float16 f16;
typedef __attribute__((ext_vector_type(8))) _Float16 f16x8;
typedef __attribute__((ext_vector_type(4))) _Float16 f16x4;
typedef __attribute__((ext_vector_type(4))) float f32x4;

__device__ __forceinline__ float lrelu(float x) { return fmaxf(x, 0.2f * x); }
__device__ __forceinline__ float elu1(float x)  { return x > 0.0f ? x : __expf(x) - 1.0f; }

// ---------------- prep ----------------
// ws: [0,32768)      w2b  f16 MFMA B-frags: w2b[((F2T*4+kf)*64+ln)*8+j] = W2[kf*32+(ln>>4)*8+j][F2T*16+(ln&15)]
//     [32768,32792)  w1a  f32[6] = {W1^T@a1[:128] (3), W1^T@a1[128:] (3)}
//     [32800,36896)  w2ab f16 B-frags of [W2@a2[:128] | W2@a2[128:]] (2 cols)
__global__ void prep(const float* __restrict__ W2, const float* __restrict__ W1,
                     const float* __restrict__ a1, const float* __restrict__ a2,
                     f16* __restrict__ w2b, float* __restrict__ w1a, f16* __restrict__ w2ab) {
    const int flat = blockIdx.x * 256 + threadIdx.x;   // 0..16383
    const int slot = flat >> 3, j = flat & 7;
    const int F2T = slot >> 8, kf = (slot >> 6) & 3, ln = slot & 63;
    const int lq = ln >> 4, lr = ln & 15;
    w2b[flat] = (f16)W2[(kf * 32 + lq * 8 + j) * 128 + F2T * 16 + lr];
    if (flat < 2048) {
        const int ks = flat >> 9, ln2 = (flat >> 3) & 63, jj = flat & 7;
        const int k = ks * 32 + ((ln2 >> 4) & 3) * 8 + jj;
        const int n = ln2 & 15;
        float v = 0.f;
        if (n < 2) {
            const float* av = a2 + n * 128;
            for (int f2 = 0; f2 < 128; ++f2) v = fmaf(W2[k * 128 + f2], av[f2], v);
        }
        w2ab[flat] = (f16)v;
    }
    if (flat >= 16381) {   // last 3 threads: w1a
        const int c = flat - 16381;
        float si = 0.f, sj = 0.f;
        for (int f = 0; f < 128; ++f) {
            const float w = W1[c * 128 + f];
            si = fmaf(w, a1[f], si);
            sj = fmaf(w, a1[128 + f], sj);
        }
        w1a[c] = si; w1a[3 + c] = sj;
    }
}

// TWO waves per batch (block=128), grid=4096. R0/R2/R3 all pinned at 46-47us:
// latency-bound, residency capped by grid at 16 waves/CU (1 wave/batch). Wave w
// owns mt/nt tiles {2w,2w+1}: hf 64->32 VGPR, bp 32->16, layer-1 bounce becomes
// wave-private (no barriers). Target ~20-24 waves/CU + halved wave lifetime.
// (128,2): VGPR cap 256 — R1 showed forcing a low cap spills catastrophically.
__global__ __launch_bounds__(128, 2)
void gat_kernel(const float* __restrict__ users,
                const float* __restrict__ W1,
                const f16* __restrict__ w2b,
                const float* __restrict__ w1a,
                const f16* __restrict__ w2ab,
                const float* __restrict__ mw1,
                const float* __restrict__ mb1,
                const float* __restrict__ mw2,
                const float* __restrict__ mb2,
                float* __restrict__ out)
{
    const int b    = blockIdx.x;
    const int tid  = threadIdx.x;
    const int wid  = tid >> 6;          // 0 or 1
    const int lane = tid & 63;
    const int lr   = lane & 15;
    const int lq   = lane >> 4;
    const int mtb  = wid * 2;           // this wave's tile base (mt/nt in {mtb, mtb+1})

    __shared__ __align__(16) char smem[9856];
    f16*   sMain = (f16*)smem;                   // 8192 B: L1 bounce (wave-private rows) / 2x2KB F-E1 bufs
    float* sSi   = (float*)(smem + 8192);        // [64]
    float* sSj   = (float*)(smem + 8448);        // [64]
    float* sPH   = (float*)(smem + 8704);        // [2][128] raw pool halves; merged into [0..127]
    float* sHid  = (float*)(smem + 9728);        // [32]

    const float* u = users + b * 192;

    // ---- scores layer 1: rank-3 exact fp32 (split: w0->sSi, w1->sSj) ----
    {
        const float x = u[lane * 3], y = u[lane * 3 + 1], z = u[lane * 3 + 2];
        if (wid == 0) sSi[lane] = fmaf(x, w1a[0], fmaf(y, w1a[1], z * w1a[2]));
        else          sSj[lane] = fmaf(x, w1a[3], fmaf(y, w1a[4], z * w1a[5]));
    }
    __syncthreads();   // #1

    // ---- softmax-1 (inv folded, exp recomputed) + product-1 -> PU^T B-frags ----
    f16x8 bfr[2];        // this wave's 2 nt tiles
    {
        float sjv[16];
        *(float4*)&sjv[0]  = *(const float4*)&sSj[lq * 8];
        *(float4*)&sjv[4]  = *(const float4*)&sSj[lq * 8 + 4];
        *(float4*)&sjv[8]  = *(const float4*)&sSj[32 + lq * 8];
        *(float4*)&sjv[12] = *(const float4*)&sSj[32 + lq * 8 + 4];
        f16x8 ap[2][2];
        #pragma unroll
        for (int m = 0; m < 2; ++m) {
            const float si = sSi[(mtb + m) * 16 + lr];
            float lsum = 0.f;
            #pragma unroll
            for (int jj = 0; jj < 8; ++jj)
                lsum += __expf(lrelu(si + sjv[jj])) + __expf(lrelu(si + sjv[8 + jj]));
            lsum += __shfl_xor(lsum, 16, 64);
            lsum += __shfl_xor(lsum, 32, 64);
            const float inv = 1.0f / lsum;
            #pragma unroll
            for (int jj = 0; jj < 8; ++jj) {
                ap[m][0][jj] = (f16)(__expf(lrelu(si + sjv[jj])) * inv);
                ap[m][1][jj] = (f16)(__expf(lrelu(si + sjv[8 + jj])) * inv);
            }
        }
        // product-1: PU^T = U^T @ P1n^T (this wave's row-tiles)
        f16x8 af2[2];
        #pragma unroll
        for (int ks = 0; ks < 2; ++ks) {
            #pragma unroll
            for (int jj = 0; jj < 8; ++jj) {
                const int node = ks * 32 + lq * 8 + jj;
                af2[ks][jj] = (lr < 3) ? (f16)u[node * 3 + lr] : (f16)0.f;
            }
        }
        #pragma unroll
        for (int m = 0; m < 2; ++m) {
            f32x4 d1 = (f32x4){0.f, 0.f, 0.f, 0.f};
            d1 = __builtin_amdgcn_mfma_f32_16x16x32_f16(af2[0], ap[m][0], d1, 0, 0, 0);
            d1 = __builtin_amdgcn_mfma_f32_16x16x32_f16(af2[1], ap[m][1], d1, 0, 0, 0);
            const float c0 = __shfl(d1[0], lr, 64);
            const float c1 = __shfl(d1[1], lr, 64);
            const float c2 = __shfl(d1[2], lr, 64);
            #pragma unroll
            for (int jj = 0; jj < 8; ++jj) bfr[m][jj] = (f16)0.f;
            if (lq == 0) {
                bfr[m][0] = (f16)c0; bfr[m][1] = (f16)c1; bfr[m][2] = (f16)c2;
            }
        }
    }

    // ====== layer-1 halves: h1^T = W1^T @ PUn^T (bounce rows wave-private) ======
    f16x8 hf[2][4];      // 32 VGPRs
    #pragma unroll
    for (int h = 0; h < 2; ++h) {
        #pragma unroll
        for (int ftl = 0; ftl < 4; ++ftl) {
            f16x8 af3;
            #pragma unroll
            for (int jj = 0; jj < 8; ++jj) af3[jj] = (f16)0.f;
            if (lq == 0) {
                #pragma unroll
                for (int jj = 0; jj < 3; ++jj)
                    af3[jj] = (f16)W1[jj * 128 + (h * 4 + ftl) * 16 + lr];
            }
            #pragma unroll
            for (int m = 0; m < 2; ++m) {
                f32x4 acc = (f32x4){0.f, 0.f, 0.f, 0.f};
                acc = __builtin_amdgcn_mfma_f32_16x16x32_f16(af3, bfr[m], acc, 0, 0, 0);
                f16x4 hv;
                #pragma unroll
                for (int r = 0; r < 4; ++r) hv[r] = (f16)elu1(acc[r]);
                const int n = (mtb + m) * 16 + lr;
                const int gg = 2 * ftl + (lq >> 1);
                *(f16x4*)&sMain[n * 64 + ((gg ^ (n & 7)) << 3) + ((lq & 1) * 4)] = hv;
            }
        }
        // wave-private rows: order writes -> reads without s_barrier
        asm volatile("s_waitcnt lgkmcnt(0)" ::: "memory");
        #pragma unroll
        for (int m = 0; m < 2; ++m) {
            const int n = (mtb + m) * 16 + lr;
            #pragma unroll
            for (int ksl = 0; ksl < 2; ++ksl)
                hf[m][h * 2 + ksl] =
                    *(const f16x8*)&sMain[n * 64 + (((ksl * 4 + lq) ^ (n & 7)) << 3)];
        }
        // reads returned before next-h overwrites the same rows
        asm volatile("s_waitcnt lgkmcnt(0)" ::: "memory");
    }

    // ---- scores layer 2 via MFMA (this wave's mt tiles) ----
    {
        f32x4 sacc[2];
        #pragma unroll
        for (int m = 0; m < 2; ++m) sacc[m] = (f32x4){0.f, 0.f, 0.f, 0.f};
        #pragma unroll
        for (int ks = 0; ks < 4; ++ks) {
            f16x8 bsw = *(const f16x8*)(w2ab + (ks * 64 + lane) * 8);
            #pragma unroll
            for (int m = 0; m < 2; ++m)
                sacc[m] = __builtin_amdgcn_mfma_f32_16x16x32_f16(hf[m][ks], bsw, sacc[m], 0, 0, 0);
        }
        __syncthreads();   // #2: both waves done reading sSi/sSj (softmax-1)
        if (lr < 2) {
            float* dst = (lr == 0) ? sSi : sSj;
            #pragma unroll
            for (int m = 0; m < 2; ++m)
                #pragma unroll
                for (int r = 0; r < 4; ++r)
                    dst[(mtb + m) * 16 + lq * 4 + r] = sacc[m][r];
        }
    }
    __syncthreads();       // #3: both halves of scores-2 visible

    // ---- softmax-2 (inv folded, exp recomputed) ----
    f16x8 bp[2][2];      // 16 VGPRs
    {
        float sjv[16];
        *(float4*)&sjv[0]  = *(const float4*)&sSj[lq * 8];
        *(float4*)&sjv[4]  = *(const float4*)&sSj[lq * 8 + 4];
        *(float4*)&sjv[8]  = *(const float4*)&sSj[32 + lq * 8];
        *(float4*)&sjv[12] = *(const float4*)&sSj[32 + lq * 8 + 4];
        #pragma unroll
        for (int m = 0; m < 2; ++m) {
            const float si = sSi[(mtb + m) * 16 + lr];
            float lsum = 0.f;
            #pragma unroll
            for (int jj = 0; jj < 8; ++jj)
                lsum += __expf(lrelu(si + sjv[jj])) + __expf(lrelu(si + sjv[8 + jj]));
            lsum += __shfl_xor(lsum, 16, 64);
            lsum += __shfl_xor(lsum, 32, 64);
            const float inv = 1.0f / lsum;
            #pragma unroll
            for (int jj = 0; jj < 8; ++jj) {
                bp[m][0][jj] = (f16)(__expf(lrelu(si + sjv[jj])) * inv);
                bp[m][1][jj] = (f16)(__expf(lrelu(si + sjv[8 + jj])) * inv);
            }
        }
    }

    // ======= fused F + E1, double-buffered (2 x 2KB in sMain) =======
    int fst[2];
    #pragma unroll
    for (int m = 0; m < 2; ++m) {
        const int gg = (mtb + m) * 2 + (lq >> 1);
        fst[m] = lr * 64 + ((gg ^ (lr & 7)) << 3) + ((lq & 1) * 4);
    }
    const int er0 = lr * 64 + ((lq ^ (lr & 7)) << 3);
    const int er1 = lr * 64 + (((4 + lq) ^ (lr & 7)) << 3);

    {   // prologue: F(0) -> buf0 (each wave writes its n-half)
        f16x8 bw2[4];
        #pragma unroll
        for (int kf = 0; kf < 4; ++kf)
            bw2[kf] = *(const f16x8*)(w2b + ((0 * 4 + kf) * 64 + lane) * 8);
        #pragma unroll
        for (int m = 0; m < 2; ++m) {
            f32x4 acc = (f32x4){0.f, 0.f, 0.f, 0.f};
            #pragma unroll
            for (int kf = 0; kf < 4; ++kf)
                acc = __builtin_amdgcn_mfma_f32_16x16x32_f16(hf[m][kf], bw2[kf], acc, 0, 0, 0);
            f16x4 hv;
            #pragma unroll
            for (int r = 0; r < 4; ++r) hv[r] = (f16)acc[r];
            *(f16x4*)&sMain[fst[m]] = hv;
        }
    }
    __syncthreads();

    #pragma unroll 1
    for (int ft = 0; ft < 8; ++ft) {
        f16* rb = sMain + ((ft & 1) << 10);
        if (ft < 7) {      // F(ft+1) -> other buffer, issued before E1(ft) reads
            f16* wb = sMain + (((ft + 1) & 1) << 10);
            f16x8 bw2[4];
            #pragma unroll
            for (int kf = 0; kf < 4; ++kf)
                bw2[kf] = *(const f16x8*)(w2b + (((ft + 1) * 4 + kf) * 64 + lane) * 8);
            #pragma unroll
            for (int m = 0; m < 2; ++m) {
                f32x4 acc = (f32x4){0.f, 0.f, 0.f, 0.f};
                #pragma unroll
                for (int kf = 0; kf < 4; ++kf)
                    acc = __builtin_amdgcn_mfma_f32_16x16x32_f16(hf[m][kf], bw2[kf], acc, 0, 0, 0);
                f16x4 hv;
                #pragma unroll
                for (int r = 0; r < 4; ++r) hv[r] = (f16)acc[r];
                *(f16x4*)&wb[fst[m]] = hv;
            }
        }

        // E1(ft): full tile read; this wave's i-rows; raw max to its pool half
        f16x8 bh0 = *(const f16x8*)&rb[er0];
        f16x8 bh1 = *(const f16x8*)&rb[er1];
        float mx = -1e30f;
        #pragma unroll
        for (int m = 0; m < 2; ++m) {
            f32x4 acc = (f32x4){0.f, 0.f, 0.f, 0.f};
            acc = __builtin_amdgcn_mfma_f32_16x16x32_f16(bp[m][0], bh0, acc, 0, 0, 0);
            acc = __builtin_amdgcn_mfma_f32_16x16x32_f16(bp[m][1], bh1, acc, 0, 0, 0);
            mx = fmaxf(mx, fmaxf(fmaxf(acc[0], acc[1]), fmaxf(acc[2], acc[3])));
        }
        mx = fmaxf(mx, __shfl_xor(mx, 16, 64));
        mx = fmaxf(mx, __shfl_xor(mx, 32, 64));
        if (lane < 16) sPH[wid * 128 + ft * 16 + lane] = mx;
        __syncthreads();   // wb visible next iter; rb reads drained before reuse
    }

    // ---- merge pool halves (max exact-assoc; elu after merge) ----
    {
        const float v = elu1(fmaxf(sPH[tid], sPH[128 + tid]));
        sPH[tid] = v;      // same-thread read-modify-write, no race
    }
    __syncthreads();

    // ================= Readout =================
    if (wid == 0) {
        const int o = lane & 31, hh = lane >> 5;
        float s0 = 0.f;
        #pragma unroll 8
        for (int kk = 0; kk < 64; ++kk) {
            const int c = hh * 64 + kk;
            s0 = fmaf(sPH[c], mw1[c * 32 + o], s0);
        }
        s0 += __shfl_xor(s0, 32, 64);
        if (lane < 32) sHid[lane] = fmaxf(s0 + mb1[o], 0.0f);
    }
    __syncthreads();
    {
        const int cbase = (wid == 0) ? 64 : 0;   // w0: B/power cols, w1: A/delta cols
        float s = mb2[cbase + lane];
        #pragma unroll 8
        for (int q = 0; q < 32; ++q)
            s = fmaf(sHid[q], mw2[q * 128 + cbase + lane], s);
        float r = fmaxf(s, 0.0f) + 1e-6f;
        float uu = r;
        #pragma unroll
        for (int m = 1; m < 64; m <<= 1) uu += __shfl_xor(uu, m, 64);
        if (wid == 0) out[b * 64 + lane]        = r / (uu + 1e-6f);
        else          out[OUT2 + b * 64 + lane] = 98.425f * r / (uu + 1e-6f);
    }
}

extern "C" void kernel_launch(void* const* d_in, const int* in_sizes, int n_in,
                              void* d_out, int out_size, void* d_ws, size_t ws_size,
                              hipStream_t stream) {
    const float* users = (const float*)d_in[0];
    const float* W1    = (const float*)d_in[1];
    const float* a1    = (const float*)d_in[2];
    const float* W2    = (const float*)d_in[3];
    const float* a2    = (const float*)d_in[4];
    const float* mw1   = (const float*)d_in[5];
    const float* mb1   = (const float*)d_in[6];
    const float* mw2   = (const float*)d_in[7];
    const float* mb2   = (const float*)d_in[8];
    float* out = (float*)d_out;

    f16*   w2b  = (f16*)d_ws;
    float* w1a  = (float*)((char*)d_ws + 32768);
    f16*   w2ab = (f16*)((char*)d_ws + 32800);

    prep<<<64, 256, 0, stream>>>(W2, W1, a1, a2, w2b, w1a, w2ab);
    gat_kernel<<<NBATCH, 128, 0, stream>>>(users, W1, w2b, w1a, w2ab,
                                           mw1, mb1, mw2, mb2, out);
}

// Round 5
// 114.722 us; speedup vs baseline: 1.0314x; 1.0314x over previous
//
#include <hip/hip_runtime.h>

#define NBATCH 4096
#define OUT2 (NBATCH * 64)

typedef _Float16 f16;
typedef __attribute__((ext_vector_type(8))) _Float16 f16x8;
typedef __attribute__((ext_vector_type(4))) _Float16 f16x4;
typedef __attribute__((ext_vector_type(4))) float f32x4;

__device__ __forceinline__ float lrelu(float x) { return fmaxf(x, 0.2f * x); }
__device__ __forceinline__ float elu1(float x)  { return x > 0.0f ? x : __expf(x) - 1.0f; }
// LDS ops from one wave execute in order; lgkmcnt(0) + memory clobber is the
// validated (R4 L1-bounce) replacement for __syncthreads on wave-private LDS.
__device__ __forceinline__ void lds_fence() {
    asm volatile("s_waitcnt lgkmcnt(0)" ::: "memory");
}

// ---------------- prep ----------------
// ws: [0,32768)      w2b  f16 MFMA B-frags: w2b[((F2T*4+kf)*64+ln)*8+j] = W2[kf*32+(ln>>4)*8+j][F2T*16+(ln&15)]
//     [32768,32792)  w1a  f32[6] = {W1^T@a1[:128] (3), W1^T@a1[128:] (3)}
//     [32800,36896)  w2ab f16 B-frags of [W2@a2[:128] | W2@a2[128:]] (2 cols)
__global__ void prep(const float* __restrict__ W2, const float* __restrict__ W1,
                     const float* __restrict__ a1, const float* __restrict__ a2,
                     f16* __restrict__ w2b, float* __restrict__ w1a, f16* __restrict__ w2ab) {
    const int flat = blockIdx.x * 256 + threadIdx.x;   // 0..16383
    const int slot = flat >> 3, j = flat & 7;
    const int F2T = slot >> 8, kf = (slot >> 6) & 3, ln = slot & 63;
    const int lq = ln >> 4, lr = ln & 15;
    w2b[flat] = (f16)W2[(kf * 32 + lq * 8 + j) * 128 + F2T * 16 + lr];
    if (flat < 2048) {
        const int ks = flat >> 9, ln2 = (flat >> 3) & 63, jj = flat & 7;
        const int k = ks * 32 + ((ln2 >> 4) & 3) * 8 + jj;
        const int n = ln2 & 15;
        float v = 0.f;
        if (n < 2) {
            const float* av = a2 + n * 128;
            for (int f2 = 0; f2 < 128; ++f2) v = fmaf(W2[k * 128 + f2], av[f2], v);
        }
        w2ab[flat] = (f16)v;
    }
    if (flat >= 16381) {   // last 3 threads: w1a
        const int c = flat - 16381;
        float si = 0.f, sj = 0.f;
        for (int f = 0; f < 128; ++f) {
            const float w = W1[c * 128 + f];
            si = fmaf(w, a1[f], si);
            sj = fmaf(w, a1[128 + f], sj);
        }
        w1a[c] = si; w1a[3 + c] = sj;
    }
}

// FOUR independent batch-waves per 256-thread block (grid 1024 = exactly 4
// blocks/CU, all resident at t=0). Each wave runs R3's verified per-batch
// program on a private 9344 B LDS slice; NO __syncthreads anywhere (waves are
// uncoupled — R4 showed barrier coupling poisons 2-wave blocks). Rationale:
// R0-R4 показали per-CU issue rate invariant (~40%) under 2x occupancy ->
// front-end bound (dispatch ramp + I-fetch). 4x fewer dispatches + 4 waves
// co-located at the same PC region share I$ lines.
// (256,2): VGPR cap 256 — R1 showed forcing a low cap spills catastrophically.
__global__ __launch_bounds__(256, 2)
void gat_kernel(const float* __restrict__ users,
                const float* __restrict__ W1,
                const f16* __restrict__ w2b,
                const float* __restrict__ w1a,
                const f16* __restrict__ w2ab,
                const float* __restrict__ mw1,
                const float* __restrict__ mb1,
                const float* __restrict__ mw2,
                const float* __restrict__ mb2,
                float* __restrict__ out)
{
    const int wid  = threadIdx.x >> 6;            // wave in block = batch slot
    const int b    = blockIdx.x * 4 + wid;
    const int lane = threadIdx.x & 63;
    const int lr   = lane & 15;
    const int lq   = lane >> 4;

    __shared__ __align__(16) char smem[4 * 9344];
    char*  sw    = smem + wid * 9344;             // wave-private slice
    f16*   sMain = (f16*)sw;                      // 8192 B: L1 bounce / 2x2KB F-E1 bufs
    float* sSi   = (float*)(sw + 8192);           // [64]
    float* sSj   = (float*)(sw + 8448);           // [64]
    float* sPool = (float*)(sw + 8704);           // [128]
    float* sHid  = (float*)(sw + 9216);           // [32]

    const float* u = users + b * 192;

    // ---- scores layer 1: rank-3 exact fp32 ----
    {
        const float x = u[lane * 3], y = u[lane * 3 + 1], z = u[lane * 3 + 2];
        sSi[lane] = fmaf(x, w1a[0], fmaf(y, w1a[1], z * w1a[2]));
        sSj[lane] = fmaf(x, w1a[3], fmaf(y, w1a[4], z * w1a[5]));
    }
    lds_fence();

    // ---- softmax-1 (inv folded into frags) + product-1 -> PU^T B-frags ----
    f16x8 bfr[4];        // normalized PU^T as B-frags (16 VGPRs)
    {
        float sjv[16];
        *(float4*)&sjv[0]  = *(const float4*)&sSj[lq * 8];
        *(float4*)&sjv[4]  = *(const float4*)&sSj[lq * 8 + 4];
        *(float4*)&sjv[8]  = *(const float4*)&sSj[32 + lq * 8];
        *(float4*)&sjv[12] = *(const float4*)&sSj[32 + lq * 8 + 4];
        f16x8 ap[4][2];
        #pragma unroll
        for (int mt = 0; mt < 4; ++mt) {
            const float si = sSi[mt * 16 + lr];
            float pv[16];
            float lsum = 0.f;
            #pragma unroll
            for (int jj = 0; jj < 8; ++jj) {
                const float t0 = si + sjv[jj];
                const float t1 = si + sjv[8 + jj];
                const float p0 = __expf(lrelu(t0));
                const float p1 = __expf(lrelu(t1));
                pv[jj] = p0; pv[8 + jj] = p1;
                lsum += p0 + p1;
            }
            lsum += __shfl_xor(lsum, 16, 64);
            lsum += __shfl_xor(lsum, 32, 64);
            const float inv = 1.0f / lsum;
            #pragma unroll
            for (int jj = 0; jj < 8; ++jj) {
                ap[mt][0][jj] = (f16)(pv[jj] * inv);
                ap[mt][1][jj] = (f16)(pv[8 + jj] * inv);
            }
        }
        // product-1: PU^T = U^T @ P1n^T  (P already normalized)
        f16x8 af2[2];
        #pragma unroll
        for (int ks = 0; ks < 2; ++ks) {
            #pragma unroll
            for (int jj = 0; jj < 8; ++jj) {
                const int node = ks * 32 + lq * 8 + jj;
                af2[ks][jj] = (lr < 3) ? (f16)u[node * 3 + lr] : (f16)0.f;
            }
        }
        #pragma unroll
        for (int nt = 0; nt < 4; ++nt) {
            f32x4 d1 = (f32x4){0.f, 0.f, 0.f, 0.f};
            d1 = __builtin_amdgcn_mfma_f32_16x16x32_f16(af2[0], ap[nt][0], d1, 0, 0, 0);
            d1 = __builtin_amdgcn_mfma_f32_16x16x32_f16(af2[1], ap[nt][1], d1, 0, 0, 0);
            const float c0 = __shfl(d1[0], lr, 64);
            const float c1 = __shfl(d1[1], lr, 64);
            const float c2 = __shfl(d1[2], lr, 64);
            #pragma unroll
            for (int jj = 0; jj < 8; ++jj) bfr[nt][jj] = (f16)0.f;
            if (lq == 0) {
                bfr[nt][0] = (f16)c0; bfr[nt][1] = (f16)c1; bfr[nt][2] = (f16)c2;
            }
        }
    }

    // ================= layer-1 halves: h1^T = W1^T @ PUn^T =================
    f16x8 hf[4][4];      // 64 VGPRs: h1 A-frags
    #pragma unroll
    for (int h = 0; h < 2; ++h) {
        #pragma unroll
        for (int ftl = 0; ftl < 4; ++ftl) {
            f16x8 af3;      // W1^T A-frag
            #pragma unroll
            for (int jj = 0; jj < 8; ++jj) af3[jj] = (f16)0.f;
            if (lq == 0) {
                #pragma unroll
                for (int jj = 0; jj < 3; ++jj)
                    af3[jj] = (f16)W1[jj * 128 + (h * 4 + ftl) * 16 + lr];
            }
            #pragma unroll
            for (int nt = 0; nt < 4; ++nt) {
                f32x4 acc = (f32x4){0.f, 0.f, 0.f, 0.f};
                acc = __builtin_amdgcn_mfma_f32_16x16x32_f16(af3, bfr[nt], acc, 0, 0, 0);
                f16x4 hv;
                #pragma unroll
                for (int r = 0; r < 4; ++r) hv[r] = (f16)elu1(acc[r]);   // inv folded upstream
                const int n = nt * 16 + lr;
                const int gg = 2 * ftl + (lq >> 1);
                *(f16x4*)&sMain[n * 64 + ((gg ^ (n & 7)) << 3) + ((lq & 1) * 4)] = hv;
            }
        }
        lds_fence();    // writes retired before frag reads
        #pragma unroll
        for (int nt = 0; nt < 4; ++nt) {
            const int n = nt * 16 + lr;
            #pragma unroll
            for (int ksl = 0; ksl < 2; ++ksl)
                hf[nt][h * 2 + ksl] =
                    *(const f16x8*)&sMain[n * 64 + (((ksl * 4 + lq) ^ (n & 7)) << 3)];
        }
        lds_fence();    // reads done before next-h overwrites same rows
    }

    // ---- scores layer 2 via MFMA ----
    {
        f32x4 sacc[4];
        #pragma unroll
        for (int mt = 0; mt < 4; ++mt) sacc[mt] = (f32x4){0.f, 0.f, 0.f, 0.f};
        #pragma unroll
        for (int ks = 0; ks < 4; ++ks) {
            f16x8 bsw = *(const f16x8*)(w2ab + (ks * 64 + lane) * 8);
            #pragma unroll
            for (int mt = 0; mt < 4; ++mt)
                sacc[mt] = __builtin_amdgcn_mfma_f32_16x16x32_f16(hf[mt][ks], bsw, sacc[mt], 0, 0, 0);
        }
        if (lr < 2) {
            float* dst = (lr == 0) ? sSi : sSj;
            #pragma unroll
            for (int mt = 0; mt < 4; ++mt)
                #pragma unroll
                for (int r = 0; r < 4; ++r)
                    dst[mt * 16 + lq * 4 + r] = sacc[mt][r];
        }
    }
    lds_fence();

    // ---- softmax-2 built once (inv2 folded into bp) ----
    f16x8 bp[4][2];      // 32 VGPRs
    {
        float sjv[16];
        *(float4*)&sjv[0]  = *(const float4*)&sSj[lq * 8];
        *(float4*)&sjv[4]  = *(const float4*)&sSj[lq * 8 + 4];
        *(float4*)&sjv[8]  = *(const float4*)&sSj[32 + lq * 8];
        *(float4*)&sjv[12] = *(const float4*)&sSj[32 + lq * 8 + 4];
        #pragma unroll
        for (int mt = 0; mt < 4; ++mt) {
            const float si = sSi[mt * 16 + lr];
            float pv[16];
            float lsum = 0.f;
            #pragma unroll
            for (int jj = 0; jj < 8; ++jj) {
                const float t0 = si + sjv[jj];
                const float t1 = si + sjv[8 + jj];
                const float p0 = __expf(lrelu(t0));
                const float p1 = __expf(lrelu(t1));
                pv[jj] = p0; pv[8 + jj] = p1;
                lsum += p0 + p1;
            }
            lsum += __shfl_xor(lsum, 16, 64);
            lsum += __shfl_xor(lsum, 32, 64);
            const float inv = 1.0f / lsum;
            #pragma unroll
            for (int jj = 0; jj < 8; ++jj) {
                bp[mt][0][jj] = (f16)(pv[jj] * inv);
                bp[mt][1][jj] = (f16)(pv[8 + jj] * inv);
            }
        }
    }

    // ======= fused F + E1, double-buffered pipeline (2 x 2KB in sMain) =======
    int fst[4];
    #pragma unroll
    for (int nt = 0; nt < 4; ++nt) {
        const int gg = nt * 2 + (lq >> 1);
        fst[nt] = lr * 64 + ((gg ^ (lr & 7)) << 3) + ((lq & 1) * 4);
    }
    const int er0 = lr * 64 + ((lq ^ (lr & 7)) << 3);
    const int er1 = lr * 64 + (((4 + lq) ^ (lr & 7)) << 3);

    {   // prologue: F(0) -> buf0
        f16x8 bw2[4];
        #pragma unroll
        for (int kf = 0; kf < 4; ++kf)
            bw2[kf] = *(const f16x8*)(w2b + ((0 * 4 + kf) * 64 + lane) * 8);
        #pragma unroll
        for (int nt = 0; nt < 4; ++nt) {
            f32x4 acc = (f32x4){0.f, 0.f, 0.f, 0.f};
            #pragma unroll
            for (int kf = 0; kf < 4; ++kf)
                acc = __builtin_amdgcn_mfma_f32_16x16x32_f16(hf[nt][kf], bw2[kf], acc, 0, 0, 0);
            f16x4 hv;
            #pragma unroll
            for (int r = 0; r < 4; ++r) hv[r] = (f16)acc[r];
            *(f16x4*)&sMain[fst[nt]] = hv;
        }
    }
    lds_fence();

    #pragma unroll 1
    for (int ft = 0; ft < 8; ++ft) {
        f16* rb = sMain + ((ft & 1) << 10);
        if (ft < 7) {      // F(ft+1) -> other buffer, issued before E1(ft) reads
            f16* wb = sMain + (((ft + 1) & 1) << 10);
            f16x8 bw2[4];
            #pragma unroll
            for (int kf = 0; kf < 4; ++kf)
                bw2[kf] = *(const f16x8*)(w2b + (((ft + 1) * 4 + kf) * 64 + lane) * 8);
            #pragma unroll
            for (int nt = 0; nt < 4; ++nt) {
                f32x4 acc = (f32x4){0.f, 0.f, 0.f, 0.f};
                #pragma unroll
                for (int kf = 0; kf < 4; ++kf)
                    acc = __builtin_amdgcn_mfma_f32_16x16x32_f16(hf[nt][kf], bw2[kf], acc, 0, 0, 0);
                f16x4 hv;
                #pragma unroll
                for (int r = 0; r < 4; ++r) hv[r] = (f16)acc[r];
                *(f16x4*)&wb[fst[nt]] = hv;
            }
        }

        // E1(ft) from rb: acc rows = i (within mt), cols = f2 (= lr)
        f16x8 bh0 = *(const f16x8*)&rb[er0];
        f16x8 bh1 = *(const f16x8*)&rb[er1];
        float mx = -1e30f;
        #pragma unroll
        for (int mt = 0; mt < 4; ++mt) {
            f32x4 acc = (f32x4){0.f, 0.f, 0.f, 0.f};
            acc = __builtin_amdgcn_mfma_f32_16x16x32_f16(bp[mt][0], bh0, acc, 0, 0, 0);
            acc = __builtin_amdgcn_mfma_f32_16x16x32_f16(bp[mt][1], bh1, acc, 0, 0, 0);
            mx = fmaxf(mx, fmaxf(fmaxf(acc[0], acc[1]), fmaxf(acc[2], acc[3])));
        }
        mx = fmaxf(mx, __shfl_xor(mx, 16, 64));
        mx = fmaxf(mx, __shfl_xor(mx, 32, 64));
        if (lane < 16) sPool[ft * 16 + lane] = elu1(mx);
        lds_fence();   // in-order DS + full drain: wb/rb hazards closed
    }

    // ================= Readout =================
    {
        const int o = lane & 31, hh = lane >> 5;
        float s0 = 0.f;
        #pragma unroll 8
        for (int kk = 0; kk < 64; ++kk) {
            const int c = hh * 64 + kk;
            s0 = fmaf(sPool[c], mw1[c * 32 + o], s0);
        }
        s0 += __shfl_xor(s0, 32, 64);
        if (lane < 32) sHid[lane] = fmaxf(s0 + mb1[o], 0.0f);
    }
    lds_fence();
    {
        float sA = mb2[lane], sB = mb2[64 + lane];
        #pragma unroll 8
        for (int q = 0; q < 32; ++q) {
            const float wA = mw2[q * 128 + lane];
            const float wB = mw2[q * 128 + 64 + lane];
            const float h0 = sHid[q];
            sA = fmaf(h0, wA, sA);  sB = fmaf(h0, wB, sB);
        }
        float rA = fmaxf(sA, 0.0f) + 1e-6f, rB = fmaxf(sB, 0.0f) + 1e-6f;
        float uA = rA, uB = rB;
        #pragma unroll
        for (int m = 1; m < 64; m <<= 1) {
            uA += __shfl_xor(uA, m, 64);  uB += __shfl_xor(uB, m, 64);
        }
        out[b * 64 + lane]        = rB / (uB + 1e-6f);
        out[OUT2 + b * 64 + lane] = 98.425f * rA / (uA + 1e-6f);
    }
}

extern "C" void kernel_launch(void* const* d_in, const int* in_sizes, int n_in,
                              void* d_out, int out_size, void* d_ws, size_t ws_size,
                              hipStream_t stream) {
    const float* users = (const float*)d_in[0];
    const float* W1    = (const float*)d_in[1];
    const float* a1    = (const float*)d_in[2];
    const float* W2    = (const float*)d_in[3];
    const float* a2    = (const float*)d_in[4];
    const float* mw1   = (const float*)d_in[5];
    const float* mb1   = (const float*)d_in[6];
    const float* mw2   = (const float*)d_in[7];
    const float* mb2   = (const float*)d_in[8];
    float* out = (float*)d_out;

    f16*   w2b  = (f16*)d_ws;
    float* w1a  = (float*)((char*)d_ws + 32768);
    f16*   w2ab = (f16*)((char*)d_ws + 32800);

    prep<<<64, 256, 0, stream>>>(W2, W1, a1, a2, w2b, w1a, w2ab);
    gat_kernel<<<NBATCH / 4, 256, 0, stream>>>(users, W1, w2b, w1a, w2ab,
                                               mw1, mb1, mw2, mb2, out);
}

// Round 7
// 114.437 us; speedup vs baseline: 1.0340x; 1.0025x over previous
//
#include <hip/hip_runtime.h>

#define NBATCH 4096
#define OUT2 (NBATCH * 64)

typedef _Float16 f16;
typedef __attribute__((ext_vector_type(8))) _Float16 f16x8;
typedef __attribute__((ext_vector_type(4))) float f32x4;

__device__ __forceinline__ float lrelu(float x) { return fmaxf(x, 0.2f * x); }
__device__ __forceinline__ float elu1(float x)  { return x > 0.0f ? x : __expf(x) - 1.0f; }
__device__ __forceinline__ void lds_fence() {
    asm volatile("s_waitcnt lgkmcnt(0)" ::: "memory");
}
// pack two f32 -> f16 (RNE, same as scalar casts) into one dword, low = a
__device__ __forceinline__ unsigned pk2(float a, float b) {
    union { f16 h[2]; unsigned u; } t;
    t.h[0] = (f16)a; t.h[1] = (f16)b;
    return t.u;
}
// 4-lane-group transpose: MFMA D-layout tile pair {t0,t1} -> A/B-frag.
// Target lane (c,q) elem j takes reg r=j&3 of tile (q>>1) from source lane
// (c, 2(q&1)+(j>>2)); s0 = c+32*(q&1), s1 = s0+16.
// R6 BUG FIX: tile select must happen AFTER the shuffle (in the destination
// lane). Selecting before shuffles the SOURCE lane's choice (its bit-5 =
// dest's q&1, not q>>1) — q=1,2 quadrants got the wrong tile. Now: shuffle
// both tiles (8 bpermute), cndmask by dest hiSel (4 selects).
__device__ __forceinline__ f16x8 xpose(unsigned p0l, unsigned p0h,
                                       unsigned p1l, unsigned p1h,
                                       int s0, int s1, bool hiSel) {
    const unsigned a0l = (unsigned)__shfl((int)p0l, s0, 64);
    const unsigned a0h = (unsigned)__shfl((int)p0h, s0, 64);
    const unsigned b0l = (unsigned)__shfl((int)p0l, s1, 64);
    const unsigned b0h = (unsigned)__shfl((int)p0h, s1, 64);
    const unsigned a1l = (unsigned)__shfl((int)p1l, s0, 64);
    const unsigned a1h = (unsigned)__shfl((int)p1h, s0, 64);
    const unsigned b1l = (unsigned)__shfl((int)p1l, s1, 64);
    const unsigned b1h = (unsigned)__shfl((int)p1h, s1, 64);
    union { unsigned u[4]; f16x8 v; } o;
    o.u[0] = hiSel ? a1l : a0l;
    o.u[1] = hiSel ? a1h : a0h;
    o.u[2] = hiSel ? b1l : b0l;
    o.u[3] = hiSel ? b1h : b0h;
    return o.v;
}

// ---------------- prep ----------------
// ws: [0,32768)      w2b  f16 MFMA B-frags: w2b[((F2T*4+kf)*64+ln)*8+j] = W2[kf*32+(ln>>4)*8+j][F2T*16+(ln&15)]
//     [32768,32792)  w1a  f32[6] = {W1^T@a1[:128] (3), W1^T@a1[128:] (3)}
//     [32800,36896)  w2ab f16 B-frags of [W2@a2[:128] | W2@a2[128:]] (2 cols)
__global__ void prep(const float* __restrict__ W2, const float* __restrict__ W1,
                     const float* __restrict__ a1, const float* __restrict__ a2,
                     f16* __restrict__ w2b, float* __restrict__ w1a, f16* __restrict__ w2ab) {
    const int flat = blockIdx.x * 256 + threadIdx.x;   // 0..16383
    const int slot = flat >> 3, j = flat & 7;
    const int F2T = slot >> 8, kf = (slot >> 6) & 3, ln = slot & 63;
    const int lq = ln >> 4, lr = ln & 15;
    w2b[flat] = (f16)W2[(kf * 32 + lq * 8 + j) * 128 + F2T * 16 + lr];
    if (flat < 2048) {
        const int ks = flat >> 9, ln2 = (flat >> 3) & 63, jj = flat & 7;
        const int k = ks * 32 + ((ln2 >> 4) & 3) * 8 + jj;
        const int n = ln2 & 15;
        float v = 0.f;
        if (n < 2) {
            const float* av = a2 + n * 128;
            for (int f2 = 0; f2 < 128; ++f2) v = fmaf(W2[k * 128 + f2], av[f2], v);
        }
        w2ab[flat] = (f16)v;
    }
    if (flat >= 16381) {   // last 3 threads: w1a
        const int c = flat - 16381;
        float si = 0.f, sj = 0.f;
        for (int f = 0; f < 128; ++f) {
            const float w = W1[c * 128 + f];
            si = fmaf(w, a1[f], si);
            sj = fmaf(w, a1[128 + f], sj);
        }
        w1a[c] = si; w1a[3 + c] = sj;
    }
}

// FOUR independent batch-waves per 256-thread block; compute core is LDS-FREE:
// both layout bounces (layer-1 D->A-frag, F->E1 D->B-frag) use in-register
// 4-lane-group transposes (pk2+xpose), bit-identical values to the LDS path.
// R0-R5: per-CU throughput invariant (~47us/16 batches) with per-wave duty
// ~10%; candidate stalls were 12 lgkmcnt(0) drains + LDS round-trips + 1.11M
// bank conflicts — all deleted here. LDS/wave: 9344 -> 1280 B.
// (256,2): VGPR cap 256 — R1 showed forcing a low cap spills catastrophically.
__global__ __launch_bounds__(256, 2)
void gat_kernel(const float* __restrict__ users,
                const float* __restrict__ W1,
                const f16* __restrict__ w2b,
                const float* __restrict__ w1a,
                const f16* __restrict__ w2ab,
                const float* __restrict__ mw1,
                const float* __restrict__ mb1,
                const float* __restrict__ mw2,
                const float* __restrict__ mb2,
                float* __restrict__ out)
{
    const int wid  = threadIdx.x >> 6;            // wave in block = batch slot
    const int b    = blockIdx.x * 4 + wid;
    const int lane = threadIdx.x & 63;
    const int lr   = lane & 15;
    const int lq   = lane >> 4;
    const int s0   = (lane & 15) | ((lane & 16) << 1);   // c + 32*(q&1)
    const int s1   = s0 + 16;
    const bool hiSel = (lane & 32) != 0;                 // q>>1

    __shared__ __align__(16) char smem[4 * 1280];
    char*  sw    = smem + wid * 1280;             // wave-private slice
    float* sSi   = (float*)(sw);                  // [64]
    float* sSj   = (float*)(sw + 256);            // [64]
    float* sPool = (float*)(sw + 512);            // [128]
    float* sHid  = (float*)(sw + 1024);           // [32]

    const float* u = users + b * 192;

    // ---- scores layer 1: rank-3 exact fp32 ----
    {
        const float x = u[lane * 3], y = u[lane * 3 + 1], z = u[lane * 3 + 2];
        sSi[lane] = fmaf(x, w1a[0], fmaf(y, w1a[1], z * w1a[2]));
        sSj[lane] = fmaf(x, w1a[3], fmaf(y, w1a[4], z * w1a[5]));
    }
    lds_fence();

    // ---- softmax-1 (inv folded into frags) + product-1 -> PU^T B-frags ----
    f16x8 bfr[4];        // normalized PU^T as B-frags (16 VGPRs)
    {
        float sjv[16];
        *(float4*)&sjv[0]  = *(const float4*)&sSj[lq * 8];
        *(float4*)&sjv[4]  = *(const float4*)&sSj[lq * 8 + 4];
        *(float4*)&sjv[8]  = *(const float4*)&sSj[32 + lq * 8];
        *(float4*)&sjv[12] = *(const float4*)&sSj[32 + lq * 8 + 4];
        f16x8 ap[4][2];
        #pragma unroll
        for (int mt = 0; mt < 4; ++mt) {
            const float si = sSi[mt * 16 + lr];
            float pv[16];
            float lsum = 0.f;
            #pragma unroll
            for (int jj = 0; jj < 8; ++jj) {
                const float p0 = __expf(lrelu(si + sjv[jj]));
                const float p1 = __expf(lrelu(si + sjv[8 + jj]));
                pv[jj] = p0; pv[8 + jj] = p1;
                lsum += p0 + p1;
            }
            lsum += __shfl_xor(lsum, 16, 64);
            lsum += __shfl_xor(lsum, 32, 64);
            const float inv = 1.0f / lsum;
            #pragma unroll
            for (int jj = 0; jj < 8; ++jj) {
                ap[mt][0][jj] = (f16)(pv[jj] * inv);
                ap[mt][1][jj] = (f16)(pv[8 + jj] * inv);
            }
        }
        // product-1: PU^T = U^T @ P1n^T  (P already normalized)
        f16x8 af2[2];
        #pragma unroll
        for (int ks = 0; ks < 2; ++ks) {
            #pragma unroll
            for (int jj = 0; jj < 8; ++jj) {
                const int node = ks * 32 + lq * 8 + jj;
                af2[ks][jj] = (lr < 3) ? (f16)u[node * 3 + lr] : (f16)0.f;
            }
        }
        #pragma unroll
        for (int nt = 0; nt < 4; ++nt) {
            f32x4 d1 = (f32x4){0.f, 0.f, 0.f, 0.f};
            d1 = __builtin_amdgcn_mfma_f32_16x16x32_f16(af2[0], ap[nt][0], d1, 0, 0, 0);
            d1 = __builtin_amdgcn_mfma_f32_16x16x32_f16(af2[1], ap[nt][1], d1, 0, 0, 0);
            const float c0 = __shfl(d1[0], lr, 64);
            const float c1 = __shfl(d1[1], lr, 64);
            const float c2 = __shfl(d1[2], lr, 64);
            #pragma unroll
            for (int jj = 0; jj < 8; ++jj) bfr[nt][jj] = (f16)0.f;
            if (lq == 0) {
                bfr[nt][0] = (f16)c0; bfr[nt][1] = (f16)c1; bfr[nt][2] = (f16)c2;
            }
        }
    }

    // ===== layer-1: h1^T = W1^T @ PUn^T, in-register transpose to A-frags =====
    // Per (h, ksl): compute D-tiles ftl = {2ksl, 2ksl+1} for all nt (32 f32
    // live), then elu+pack+xpose -> hf[nt][2h+ksl]. No LDS, no fences.
    f16x8 hf[4][4];      // 64 VGPRs: h1 A-frags
    #pragma unroll
    for (int h = 0; h < 2; ++h) {
        #pragma unroll
        for (int ksl = 0; ksl < 2; ++ksl) {
            f32x4 acc[4][2];
            #pragma unroll
            for (int tp = 0; tp < 2; ++tp) {
                const int ftl = 2 * ksl + tp;
                f16x8 af3;      // W1^T A-frag
                #pragma unroll
                for (int jj = 0; jj < 8; ++jj) af3[jj] = (f16)0.f;
                if (lq == 0) {
                    #pragma unroll
                    for (int jj = 0; jj < 3; ++jj)
                        af3[jj] = (f16)W1[jj * 128 + (h * 4 + ftl) * 16 + lr];
                }
                #pragma unroll
                for (int nt = 0; nt < 4; ++nt) {
                    acc[nt][tp] = (f32x4){0.f, 0.f, 0.f, 0.f};
                    acc[nt][tp] = __builtin_amdgcn_mfma_f32_16x16x32_f16(af3, bfr[nt], acc[nt][tp], 0, 0, 0);
                }
            }
            #pragma unroll
            for (int nt = 0; nt < 4; ++nt) {
                const unsigned p0l = pk2(elu1(acc[nt][0][0]), elu1(acc[nt][0][1]));
                const unsigned p0h = pk2(elu1(acc[nt][0][2]), elu1(acc[nt][0][3]));
                const unsigned p1l = pk2(elu1(acc[nt][1][0]), elu1(acc[nt][1][1]));
                const unsigned p1h = pk2(elu1(acc[nt][1][2]), elu1(acc[nt][1][3]));
                hf[nt][h * 2 + ksl] = xpose(p0l, p0h, p1l, p1h, s0, s1, hiSel);
            }
        }
    }

    // ---- scores layer 2 via MFMA ----
    {
        f32x4 sacc[4];
        #pragma unroll
        for (int mt = 0; mt < 4; ++mt) sacc[mt] = (f32x4){0.f, 0.f, 0.f, 0.f};
        #pragma unroll
        for (int ks = 0; ks < 4; ++ks) {
            f16x8 bsw = *(const f16x8*)(w2ab + (ks * 64 + lane) * 8);
            #pragma unroll
            for (int mt = 0; mt < 4; ++mt)
                sacc[mt] = __builtin_amdgcn_mfma_f32_16x16x32_f16(hf[mt][ks], bsw, sacc[mt], 0, 0, 0);
        }
        lds_fence();   // softmax-1's sSi/sSj reads ordered before overwrite
        if (lr < 2) {
            float* dst = (lr == 0) ? sSi : sSj;
            #pragma unroll
            for (int mt = 0; mt < 4; ++mt)
                #pragma unroll
                for (int r = 0; r < 4; ++r)
                    dst[mt * 16 + lq * 4 + r] = sacc[mt][r];
        }
    }
    lds_fence();

    // ---- softmax-2 built once (inv2 folded into bp) ----
    f16x8 bp[4][2];      // 32 VGPRs
    {
        float sjv[16];
        *(float4*)&sjv[0]  = *(const float4*)&sSj[lq * 8];
        *(float4*)&sjv[4]  = *(const float4*)&sSj[lq * 8 + 4];
        *(float4*)&sjv[8]  = *(const float4*)&sSj[32 + lq * 8];
        *(float4*)&sjv[12] = *(const float4*)&sSj[32 + lq * 8 + 4];
        #pragma unroll
        for (int mt = 0; mt < 4; ++mt) {
            const float si = sSi[mt * 16 + lr];
            float pv[16];
            float lsum = 0.f;
            #pragma unroll
            for (int jj = 0; jj < 8; ++jj) {
                const float p0 = __expf(lrelu(si + sjv[jj]));
                const float p1 = __expf(lrelu(si + sjv[8 + jj]));
                pv[jj] = p0; pv[8 + jj] = p1;
                lsum += p0 + p1;
            }
            lsum += __shfl_xor(lsum, 16, 64);
            lsum += __shfl_xor(lsum, 32, 64);
            const float inv = 1.0f / lsum;
            #pragma unroll
            for (int jj = 0; jj < 8; ++jj) {
                bp[mt][0][jj] = (f16)(pv[jj] * inv);
                bp[mt][1][jj] = (f16)(pv[8 + jj] * inv);
            }
        }
    }

    // ======= fused F + E1, fully in-register (no LDS, no fences) =======
    // F: Wh2 tile [16 f2][64 n] in D-layout; pack -> xpose -> B-frags bh0/bh1
    // (n in [0,32) from nt{0,1}, n in [32,64) from nt{2,3}); E1 operand-swapped.
    #pragma unroll 1
    for (int ft = 0; ft < 8; ++ft) {
        f16x8 bw2[4];
        #pragma unroll
        for (int kf = 0; kf < 4; ++kf)
            bw2[kf] = *(const f16x8*)(w2b + ((ft * 4 + kf) * 64 + lane) * 8);
        unsigned pkq[4][2];
        #pragma unroll
        for (int nt = 0; nt < 4; ++nt) {
            f32x4 acc = (f32x4){0.f, 0.f, 0.f, 0.f};
            #pragma unroll
            for (int kf = 0; kf < 4; ++kf)
                acc = __builtin_amdgcn_mfma_f32_16x16x32_f16(hf[nt][kf], bw2[kf], acc, 0, 0, 0);
            pkq[nt][0] = pk2(acc[0], acc[1]);
            pkq[nt][1] = pk2(acc[2], acc[3]);
        }
        const f16x8 bh0 = xpose(pkq[0][0], pkq[0][1], pkq[1][0], pkq[1][1], s0, s1, hiSel);
        const f16x8 bh1 = xpose(pkq[2][0], pkq[2][1], pkq[3][0], pkq[3][1], s0, s1, hiSel);

        float mx = -1e30f;
        #pragma unroll
        for (int mt = 0; mt < 4; ++mt) {
            f32x4 acc = (f32x4){0.f, 0.f, 0.f, 0.f};
            acc = __builtin_amdgcn_mfma_f32_16x16x32_f16(bp[mt][0], bh0, acc, 0, 0, 0);
            acc = __builtin_amdgcn_mfma_f32_16x16x32_f16(bp[mt][1], bh1, acc, 0, 0, 0);
            mx = fmaxf(mx, fmaxf(fmaxf(acc[0], acc[1]), fmaxf(acc[2], acc[3])));
        }
        mx = fmaxf(mx, __shfl_xor(mx, 16, 64));
        mx = fmaxf(mx, __shfl_xor(mx, 32, 64));
        if (lane < 16) sPool[ft * 16 + lane] = elu1(mx);
    }
    lds_fence();

    // ================= Readout =================
    {
        const int o = lane & 31, hh = lane >> 5;
        float s0r = 0.f;
        #pragma unroll 8
        for (int kk = 0; kk < 64; ++kk) {
            const int c = hh * 64 + kk;
            s0r = fmaf(sPool[c], mw1[c * 32 + o], s0r);
        }
        s0r += __shfl_xor(s0r, 32, 64);
        if (lane < 32) sHid[lane] = fmaxf(s0r + mb1[o], 0.0f);
    }
    lds_fence();
    {
        float sA = mb2[lane], sB = mb2[64 + lane];
        #pragma unroll 8
        for (int q = 0; q < 32; ++q) {
            const float wA = mw2[q * 128 + lane];
            const float wB = mw2[q * 128 + 64 + lane];
            const float h0 = sHid[q];
            sA = fmaf(h0, wA, sA);  sB = fmaf(h0, wB, sB);
        }
        float rA = fmaxf(sA, 0.0f) + 1e-6f, rB = fmaxf(sB, 0.0f) + 1e-6f;
        float uA = rA, uB = rB;
        #pragma unroll
        for (int m = 1; m < 64; m <<= 1) {
            uA += __shfl_xor(uA, m, 64);  uB += __shfl_xor(uB, m, 64);
        }
        out[b * 64 + lane]        = rB / (uB + 1e-6f);
        out[OUT2 + b * 64 + lane] = 98.425f * rA / (uA + 1e-6f);
    }
}

extern "C" void kernel_launch(void* const* d_in, const int* in_sizes, int n_in,
                              void* d_out, int out_size, void* d_ws, size_t ws_size,
                              hipStream_t stream) {
    const float* users = (const float*)d_in[0];
    const float* W1    = (const float*)d_in[1];
    const float* a1    = (const float*)d_in[2];
    const float* W2    = (const float*)d_in[3];
    const float* a2    = (const float*)d_in[4];
    const float* mw1   = (const float*)d_in[5];
    const float* mb1   = (const float*)d_in[6];
    const float* mw2   = (const float*)d_in[7];
    const float* mb2   = (const float*)d_in[8];
    float* out = (float*)d_out;

    f16*   w2b  = (f16*)d_ws;
    float* w1a  = (float*)((char*)d_ws + 32768);
    f16*   w2ab = (f16*)((char*)d_ws + 32800);

    prep<<<64, 256, 0, stream>>>(W2, W1, a1, a2, w2b, w1a, w2ab);
    gat_kernel<<<NBATCH / 4, 256, 0, stream>>>(users, W1, w2b, w1a, w2ab,
                                               mw1, mb1, mw2, mb2, out);
}

// Round 8
// 113.380 us; speedup vs baseline: 1.0436x; 1.0093x over previous
//
#include <hip/hip_runtime.h>

#define NBATCH 4096
#define OUT2 (NBATCH * 64)

typedef _Float16 f16;
typedef __attribute__((ext_vector_type(8))) _Float16 f16x8;
typedef __attribute__((ext_vector_type(4))) float f32x4;

__device__ __forceinline__ float lrelu(float x) { return fmaxf(x, 0.2f * x); }
__device__ __forceinline__ float elu1(float x)  { return x > 0.0f ? x : __expf(x) - 1.0f; }
__device__ __forceinline__ void lds_fence() {
    asm volatile("s_waitcnt lgkmcnt(0)" ::: "memory");
}
// pack two f32 -> f16 (RNE, same as scalar casts) into one dword, low = a
__device__ __forceinline__ unsigned pk2(float a, float b) {
    union { f16 h[2]; unsigned u; } t;
    t.h[0] = (f16)a; t.h[1] = (f16)b;
    return t.u;
}
// 4-lane-group transpose: MFMA D-layout tile pair {t0,t1} -> A/B-frag.
// Target lane (c,q) elem j takes reg r=j&3 of tile (q>>1) from source lane
// (c, 2(q&1)+(j>>2)); s0 = c+32*(q&1), s1 = s0+16. Tile select AFTER the
// shuffle, in the destination lane (R6 bug: selecting before uses the source
// lane's predicate).
__device__ __forceinline__ f16x8 xpose(unsigned p0l, unsigned p0h,
                                       unsigned p1l, unsigned p1h,
                                       int s0, int s1, bool hiSel) {
    const unsigned a0l = (unsigned)__shfl((int)p0l, s0, 64);
    const unsigned a0h = (unsigned)__shfl((int)p0h, s0, 64);
    const unsigned b0l = (unsigned)__shfl((int)p0l, s1, 64);
    const unsigned b0h = (unsigned)__shfl((int)p0h, s1, 64);
    const unsigned a1l = (unsigned)__shfl((int)p1l, s0, 64);
    const unsigned a1h = (unsigned)__shfl((int)p1h, s0, 64);
    const unsigned b1l = (unsigned)__shfl((int)p1l, s1, 64);
    const unsigned b1h = (unsigned)__shfl((int)p1h, s1, 64);
    union { unsigned u[4]; f16x8 v; } o;
    o.u[0] = hiSel ? a1l : a0l;
    o.u[1] = hiSel ? a1h : a0h;
    o.u[2] = hiSel ? b1l : b0l;
    o.u[3] = hiSel ? b1h : b0h;
    return o.v;
}

// ---------------- prep ----------------
// ws: [0,32768)      w2b  f16 MFMA B-frags: w2b[((F2T*4+kf)*64+ln)*8+j] = W2[kf*32+(ln>>4)*8+j][F2T*16+(ln&15)]
//     [32768,32792)  w1a  f32[6] = {W1^T@a1[:128] (3), W1^T@a1[128:] (3)}
//     [32800,36896)  w2ab f16 B-frags of [W2@a2[:128] | W2@a2[128:]] (2 cols)
__global__ void prep(const float* __restrict__ W2, const float* __restrict__ W1,
                     const float* __restrict__ a1, const float* __restrict__ a2,
                     f16* __restrict__ w2b, float* __restrict__ w1a, f16* __restrict__ w2ab) {
    const int flat = blockIdx.x * 256 + threadIdx.x;   // 0..16383
    const int slot = flat >> 3, j = flat & 7;
    const int F2T = slot >> 8, kf = (slot >> 6) & 3, ln = slot & 63;
    const int lq = ln >> 4, lr = ln & 15;
    w2b[flat] = (f16)W2[(kf * 32 + lq * 8 + j) * 128 + F2T * 16 + lr];
    if (flat < 2048) {
        const int ks = flat >> 9, ln2 = (flat >> 3) & 63, jj = flat & 7;
        const int k = ks * 32 + ((ln2 >> 4) & 3) * 8 + jj;
        const int n = ln2 & 15;
        float v = 0.f;
        if (n < 2) {
            const float* av = a2 + n * 128;
            for (int f2 = 0; f2 < 128; ++f2) v = fmaf(W2[k * 128 + f2], av[f2], v);
        }
        w2ab[flat] = (f16)v;
    }
    if (flat >= 16381) {   // last 3 threads: w1a
        const int c = flat - 16381;
        float si = 0.f, sj = 0.f;
        for (int f = 0; f < 128; ++f) {
            const float w = W1[c * 128 + f];
            si = fmaf(w, a1[f], si);
            sj = fmaf(w, a1[128 + f], sj);
        }
        w1a[c] = si; w1a[3 + c] = sj;
    }
}

// FOUR independent batch-waves per 256-thread block; LDS-free compute core.
// R0-R7 synthesis: 16 batches/CU is fixed by the problem; every arrangement
// lands at ~46us with all pipes <50% => wall time = ONE batch's exposed
// dependency-chain latency, all batches concurrent. The remaining lever is
// intra-wave ILP (R0 proved 2 interleaved streams are free). The F/E1 loop's
// 8 iterations are mutually independent and were force-serialized by
// `#pragma unroll 1` (LDS-dbuf leftover). Now fully unrolled -> compiler
// interleaves the 8 chains (MFMA/bpermute/shfl latencies covered by
// neighboring iterations' independent ops).
// (256,2): VGPR cap 256 — R1 showed forcing a low cap spills catastrophically.
__global__ __launch_bounds__(256, 2)
void gat_kernel(const float* __restrict__ users,
                const float* __restrict__ W1,
                const f16* __restrict__ w2b,
                const float* __restrict__ w1a,
                const f16* __restrict__ w2ab,
                const float* __restrict__ mw1,
                const float* __restrict__ mb1,
                const float* __restrict__ mw2,
                const float* __restrict__ mb2,
                float* __restrict__ out)
{
    const int wid  = threadIdx.x >> 6;            // wave in block = batch slot
    const int b    = blockIdx.x * 4 + wid;
    const int lane = threadIdx.x & 63;
    const int lr   = lane & 15;
    const int lq   = lane >> 4;
    const int s0   = (lane & 15) | ((lane & 16) << 1);   // c + 32*(q&1)
    const int s1   = s0 + 16;
    const bool hiSel = (lane & 32) != 0;                 // q>>1

    __shared__ __align__(16) char smem[4 * 1280];
    char*  sw    = smem + wid * 1280;             // wave-private slice
    float* sSi   = (float*)(sw);                  // [64]
    float* sSj   = (float*)(sw + 256);            // [64]
    float* sPool = (float*)(sw + 512);            // [128]
    float* sHid  = (float*)(sw + 1024);           // [32]

    const float* u = users + b * 192;

    // ---- scores layer 1: rank-3 exact fp32 ----
    {
        const float x = u[lane * 3], y = u[lane * 3 + 1], z = u[lane * 3 + 2];
        sSi[lane] = fmaf(x, w1a[0], fmaf(y, w1a[1], z * w1a[2]));
        sSj[lane] = fmaf(x, w1a[3], fmaf(y, w1a[4], z * w1a[5]));
    }
    lds_fence();

    // ---- softmax-1 (inv folded into frags) + product-1 -> PU^T B-frags ----
    f16x8 bfr[4];        // normalized PU^T as B-frags (16 VGPRs)
    {
        float sjv[16];
        *(float4*)&sjv[0]  = *(const float4*)&sSj[lq * 8];
        *(float4*)&sjv[4]  = *(const float4*)&sSj[lq * 8 + 4];
        *(float4*)&sjv[8]  = *(const float4*)&sSj[32 + lq * 8];
        *(float4*)&sjv[12] = *(const float4*)&sSj[32 + lq * 8 + 4];
        f16x8 ap[4][2];
        #pragma unroll
        for (int mt = 0; mt < 4; ++mt) {
            const float si = sSi[mt * 16 + lr];
            float pv[16];
            float lsum = 0.f;
            #pragma unroll
            for (int jj = 0; jj < 8; ++jj) {
                const float p0 = __expf(lrelu(si + sjv[jj]));
                const float p1 = __expf(lrelu(si + sjv[8 + jj]));
                pv[jj] = p0; pv[8 + jj] = p1;
                lsum += p0 + p1;
            }
            lsum += __shfl_xor(lsum, 16, 64);
            lsum += __shfl_xor(lsum, 32, 64);
            const float inv = 1.0f / lsum;
            #pragma unroll
            for (int jj = 0; jj < 8; ++jj) {
                ap[mt][0][jj] = (f16)(pv[jj] * inv);
                ap[mt][1][jj] = (f16)(pv[8 + jj] * inv);
            }
        }
        // product-1: PU^T = U^T @ P1n^T  (P already normalized)
        f16x8 af2[2];
        #pragma unroll
        for (int ks = 0; ks < 2; ++ks) {
            #pragma unroll
            for (int jj = 0; jj < 8; ++jj) {
                const int node = ks * 32 + lq * 8 + jj;
                af2[ks][jj] = (lr < 3) ? (f16)u[node * 3 + lr] : (f16)0.f;
            }
        }
        #pragma unroll
        for (int nt = 0; nt < 4; ++nt) {
            f32x4 d1 = (f32x4){0.f, 0.f, 0.f, 0.f};
            d1 = __builtin_amdgcn_mfma_f32_16x16x32_f16(af2[0], ap[nt][0], d1, 0, 0, 0);
            d1 = __builtin_amdgcn_mfma_f32_16x16x32_f16(af2[1], ap[nt][1], d1, 0, 0, 0);
            const float c0 = __shfl(d1[0], lr, 64);
            const float c1 = __shfl(d1[1], lr, 64);
            const float c2 = __shfl(d1[2], lr, 64);
            #pragma unroll
            for (int jj = 0; jj < 8; ++jj) bfr[nt][jj] = (f16)0.f;
            if (lq == 0) {
                bfr[nt][0] = (f16)c0; bfr[nt][1] = (f16)c1; bfr[nt][2] = (f16)c2;
            }
        }
    }

    // ===== layer-1: h1^T = W1^T @ PUn^T, in-register transpose to A-frags =====
    // Per (h, ksl): compute D-tiles ftl = {2ksl, 2ksl+1} for all nt (32 f32
    // live), then elu+pack+xpose -> hf[nt][2h+ksl]. No LDS, no fences.
    f16x8 hf[4][4];      // 64 VGPRs: h1 A-frags
    #pragma unroll
    for (int h = 0; h < 2; ++h) {
        #pragma unroll
        for (int ksl = 0; ksl < 2; ++ksl) {
            f32x4 acc[4][2];
            #pragma unroll
            for (int tp = 0; tp < 2; ++tp) {
                const int ftl = 2 * ksl + tp;
                f16x8 af3;      // W1^T A-frag
                #pragma unroll
                for (int jj = 0; jj < 8; ++jj) af3[jj] = (f16)0.f;
                if (lq == 0) {
                    #pragma unroll
                    for (int jj = 0; jj < 3; ++jj)
                        af3[jj] = (f16)W1[jj * 128 + (h * 4 + ftl) * 16 + lr];
                }
                #pragma unroll
                for (int nt = 0; nt < 4; ++nt) {
                    acc[nt][tp] = (f32x4){0.f, 0.f, 0.f, 0.f};
                    acc[nt][tp] = __builtin_amdgcn_mfma_f32_16x16x32_f16(af3, bfr[nt], acc[nt][tp], 0, 0, 0);
                }
            }
            #pragma unroll
            for (int nt = 0; nt < 4; ++nt) {
                const unsigned p0l = pk2(elu1(acc[nt][0][0]), elu1(acc[nt][0][1]));
                const unsigned p0h = pk2(elu1(acc[nt][0][2]), elu1(acc[nt][0][3]));
                const unsigned p1l = pk2(elu1(acc[nt][1][0]), elu1(acc[nt][1][1]));
                const unsigned p1h = pk2(elu1(acc[nt][1][2]), elu1(acc[nt][1][3]));
                hf[nt][h * 2 + ksl] = xpose(p0l, p0h, p1l, p1h, s0, s1, hiSel);
            }
        }
    }

    // ---- scores layer 2 via MFMA ----
    {
        f32x4 sacc[4];
        #pragma unroll
        for (int mt = 0; mt < 4; ++mt) sacc[mt] = (f32x4){0.f, 0.f, 0.f, 0.f};
        #pragma unroll
        for (int ks = 0; ks < 4; ++ks) {
            f16x8 bsw = *(const f16x8*)(w2ab + (ks * 64 + lane) * 8);
            #pragma unroll
            for (int mt = 0; mt < 4; ++mt)
                sacc[mt] = __builtin_amdgcn_mfma_f32_16x16x32_f16(hf[mt][ks], bsw, sacc[mt], 0, 0, 0);
        }
        lds_fence();   // softmax-1's sSi/sSj reads ordered before overwrite
        if (lr < 2) {
            float* dst = (lr == 0) ? sSi : sSj;
            #pragma unroll
            for (int mt = 0; mt < 4; ++mt)
                #pragma unroll
                for (int r = 0; r < 4; ++r)
                    dst[mt * 16 + lq * 4 + r] = sacc[mt][r];
        }
    }
    lds_fence();

    // ---- softmax-2 built once (inv2 folded into bp) ----
    f16x8 bp[4][2];      // 32 VGPRs
    {
        float sjv[16];
        *(float4*)&sjv[0]  = *(const float4*)&sSj[lq * 8];
        *(float4*)&sjv[4]  = *(const float4*)&sSj[lq * 8 + 4];
        *(float4*)&sjv[8]  = *(const float4*)&sSj[32 + lq * 8];
        *(float4*)&sjv[12] = *(const float4*)&sSj[32 + lq * 8 + 4];
        #pragma unroll
        for (int mt = 0; mt < 4; ++mt) {
            const float si = sSi[mt * 16 + lr];
            float pv[16];
            float lsum = 0.f;
            #pragma unroll
            for (int jj = 0; jj < 8; ++jj) {
                const float p0 = __expf(lrelu(si + sjv[jj]));
                const float p1 = __expf(lrelu(si + sjv[8 + jj]));
                pv[jj] = p0; pv[8 + jj] = p1;
                lsum += p0 + p1;
            }
            lsum += __shfl_xor(lsum, 16, 64);
            lsum += __shfl_xor(lsum, 32, 64);
            const float inv = 1.0f / lsum;
            #pragma unroll
            for (int jj = 0; jj < 8; ++jj) {
                bp[mt][0][jj] = (f16)(pv[jj] * inv);
                bp[mt][1][jj] = (f16)(pv[8 + jj] * inv);
            }
        }
    }

    // ======= fused F + E1, fully in-register, FULLY UNROLLED =======
    // The 8 ft iterations are mutually independent (hf/bp loop-invariant,
    // sPool writes disjoint). Full unroll -> compiler interleaves the chains;
    // this is the intra-wave ILP that R0 proved free at the batch level.
    #pragma unroll
    for (int ft = 0; ft < 8; ++ft) {
        f16x8 bw2[4];
        #pragma unroll
        for (int kf = 0; kf < 4; ++kf)
            bw2[kf] = *(const f16x8*)(w2b + ((ft * 4 + kf) * 64 + lane) * 8);
        unsigned pkq[4][2];
        #pragma unroll
        for (int nt = 0; nt < 4; ++nt) {
            f32x4 acc = (f32x4){0.f, 0.f, 0.f, 0.f};
            #pragma unroll
            for (int kf = 0; kf < 4; ++kf)
                acc = __builtin_amdgcn_mfma_f32_16x16x32_f16(hf[nt][kf], bw2[kf], acc, 0, 0, 0);
            pkq[nt][0] = pk2(acc[0], acc[1]);
            pkq[nt][1] = pk2(acc[2], acc[3]);
        }
        const f16x8 bh0 = xpose(pkq[0][0], pkq[0][1], pkq[1][0], pkq[1][1], s0, s1, hiSel);
        const f16x8 bh1 = xpose(pkq[2][0], pkq[2][1], pkq[3][0], pkq[3][1], s0, s1, hiSel);

        float mx = -1e30f;
        #pragma unroll
        for (int mt = 0; mt < 4; ++mt) {
            f32x4 acc = (f32x4){0.f, 0.f, 0.f, 0.f};
            acc = __builtin_amdgcn_mfma_f32_16x16x32_f16(bp[mt][0], bh0, acc, 0, 0, 0);
            acc = __builtin_amdgcn_mfma_f32_16x16x32_f16(bp[mt][1], bh1, acc, 0, 0, 0);
            mx = fmaxf(mx, fmaxf(fmaxf(acc[0], acc[1]), fmaxf(acc[2], acc[3])));
        }
        mx = fmaxf(mx, __shfl_xor(mx, 16, 64));
        mx = fmaxf(mx, __shfl_xor(mx, 32, 64));
        if (lane < 16) sPool[ft * 16 + lane] = elu1(mx);
    }
    lds_fence();

    // ================= Readout =================
    {
        const int o = lane & 31, hh = lane >> 5;
        float s0r = 0.f;
        #pragma unroll 8
        for (int kk = 0; kk < 64; ++kk) {
            const int c = hh * 64 + kk;
            s0r = fmaf(sPool[c], mw1[c * 32 + o], s0r);
        }
        s0r += __shfl_xor(s0r, 32, 64);
        if (lane < 32) sHid[lane] = fmaxf(s0r + mb1[o], 0.0f);
    }
    lds_fence();
    {
        float sA = mb2[lane], sB = mb2[64 + lane];
        #pragma unroll 8
        for (int q = 0; q < 32; ++q) {
            const float wA = mw2[q * 128 + lane];
            const float wB = mw2[q * 128 + 64 + lane];
            const float h0 = sHid[q];
            sA = fmaf(h0, wA, sA);  sB = fmaf(h0, wB, sB);
        }
        float rA = fmaxf(sA, 0.0f) + 1e-6f, rB = fmaxf(sB, 0.0f) + 1e-6f;
        float uA = rA, uB = rB;
        #pragma unroll
        for (int m = 1; m < 64; m <<= 1) {
            uA += __shfl_xor(uA, m, 64);  uB += __shfl_xor(uB, m, 64);
        }
        out[b * 64 + lane]        = rB / (uB + 1e-6f);
        out[OUT2 + b * 64 + lane] = 98.425f * rA / (uA + 1e-6f);
    }
}

extern "C" void kernel_launch(void* const* d_in, const int* in_sizes, int n_in,
                              void* d_out, int out_size, void* d_ws, size_t ws_size,
                              hipStream_t stream) {
    const float* users = (const float*)d_in[0];
    const float* W1    = (const float*)d_in[1];
    const float* a1    = (const float*)d_in[2];
    const float* W2    = (const float*)d_in[3];
    const float* a2    = (const float*)d_in[4];
    const float* mw1   = (const float*)d_in[5];
    const float* mb1   = (const float*)d_in[6];
    const float* mw2   = (const float*)d_in[7];
    const float* mb2   = (const float*)d_in[8];
    float* out = (float*)d_out;

    f16*   w2b  = (f16*)d_ws;
    float* w1a  = (float*)((char*)d_ws + 32768);
    f16*   w2ab = (f16*)((char*)d_ws + 32800);

    prep<<<64, 256, 0, stream>>>(W2, W1, a1, a2, w2b, w1a, w2ab);
    gat_kernel<<<NBATCH / 4, 256, 0, stream>>>(users, W1, w2b, w1a, w2ab,
                                               mw1, mb1, mw2, mb2, out);
}